// Round 1
// baseline (2690.876 us; speedup 1.0000x reference)
//
#include <hip/hip_runtime.h>

#define FEAT 128

__global__ void gcmc_zero_kernel(float4* __restrict__ out, int n4) {
    int i = blockIdx.x * blockDim.x + threadIdx.x;
    if (i < n4) out[i] = make_float4(0.f, 0.f, 0.f, 0.f);
}

// 32 threads per edge; each thread handles 4 contiguous features.
__global__ void gcmc_scatter_kernel(const float* __restrict__ weight,
                                    const float* __restrict__ cj,
                                    const int* __restrict__ src,
                                    const int* __restrict__ dst,
                                    float* __restrict__ out,
                                    int n_edges) {
    int t = blockIdx.x * blockDim.x + threadIdx.x;
    int e = t >> 5;              // edge index
    int f = (t & 31) << 2;       // feature offset (float index, 0..124)
    if (e >= n_edges) return;
    int s = src[e];
    int d = dst[e];
    float c = cj[s];
    const float4 w = *reinterpret_cast<const float4*>(weight + (size_t)s * FEAT + f);
    float* o = out + (size_t)d * FEAT + f;
    // Hardware global_atomic_add_f32 (atomicAdd(float*) would emit a CAS loop
    // without -munsafe-fp-atomics).
    unsafeAtomicAdd(o + 0, w.x * c);
    unsafeAtomicAdd(o + 1, w.y * c);
    unsafeAtomicAdd(o + 2, w.z * c);
    unsafeAtomicAdd(o + 3, w.w * c);
}

__global__ void gcmc_scale_kernel(float4* __restrict__ out,
                                  const float* __restrict__ ci, int n4) {
    int i = blockIdx.x * blockDim.x + threadIdx.x;
    if (i < n4) {
        float c = ci[i >> 5];    // node = (i*4)/128 = i/32
        float4 v = out[i];
        v.x *= c; v.y *= c; v.z *= c; v.w *= c;
        out[i] = v;
    }
}

extern "C" void kernel_launch(void* const* d_in, const int* in_sizes, int n_in,
                              void* d_out, int out_size, void* d_ws, size_t ws_size,
                              hipStream_t stream) {
    const float* weight = (const float*)d_in[0];
    const float* cj     = (const float*)d_in[1];
    const float* ci     = (const float*)d_in[2];
    const int*   src    = (const int*)d_in[3];
    const int*   dst    = (const int*)d_in[4];
    float* out = (float*)d_out;

    const int n_nodes = in_sizes[1];           // cj is [N,1]
    const int n_edges = in_sizes[3];
    const int total   = n_nodes * FEAT;
    const int n4      = total >> 2;

    // 1) zero the accumulator (d_out is poisoned, never re-poisoned between replays)
    gcmc_zero_kernel<<<(n4 + 255) / 256, 256, 0, stream>>>((float4*)out, n4);

    // 2) edge-parallel gather + atomic scatter-add
    const long threads = (long)n_edges * 32;
    gcmc_scatter_kernel<<<(int)((threads + 255) / 256), 256, 0, stream>>>(
        weight, cj, src, dst, out, n_edges);

    // 3) dst-side normalize by ci, in place
    gcmc_scale_kernel<<<(n4 + 255) / 256, 256, 0, stream>>>((float4*)out, ci, n4);
}

// Round 2
// 282.945 us; speedup vs baseline: 9.5102x; 9.5102x over previous
//
#include <hip/hip_runtime.h>

#define FEAT 128

// ---------------------------------------------------------------------------
// CSR-build + register-accumulate path (no float atomics)
// ---------------------------------------------------------------------------

__global__ void zero_ints_kernel(int* __restrict__ p, int n) {
    int i = blockIdx.x * blockDim.x + threadIdx.x;
    if (i < n) p[i] = 0;
}

__global__ void hist_kernel(const int* __restrict__ dst, int* __restrict__ counts, int E) {
    int i = blockIdx.x * blockDim.x + threadIdx.x;
    if (i < E) atomicAdd(&counts[dst[i]], 1);
}

// Per-block sum of 256 counts -> bsum[block]
__global__ void block_sum_kernel(const int* __restrict__ counts, int* __restrict__ bsum, int N) {
    __shared__ int s[256];
    int i = blockIdx.x * 256 + threadIdx.x;
    s[threadIdx.x] = (i < N) ? counts[i] : 0;
    __syncthreads();
    for (int off = 128; off > 0; off >>= 1) {
        if (threadIdx.x < off) s[threadIdx.x] += s[threadIdx.x + off];
        __syncthreads();
    }
    if (threadIdx.x == 0) bsum[blockIdx.x] = s[0];
}

// Single-block exclusive scan of bsum[0..nb), nb <= 512
__global__ void scan_bsum_kernel(int* __restrict__ bsum, int nb) {
    __shared__ int s[512];
    int t = threadIdx.x;
    int mine = (t < nb) ? bsum[t] : 0;
    s[t] = mine;
    __syncthreads();
    for (int off = 1; off < 512; off <<= 1) {
        int v = (t >= off) ? s[t - off] : 0;
        __syncthreads();
        s[t] += v;
        __syncthreads();
    }
    if (t < nb) bsum[t] = s[t] - mine;   // exclusive
}

// Per-block exclusive scan of counts + block offset -> offsets; offsets[N]=E
__global__ void scan_counts_kernel(const int* __restrict__ counts, const int* __restrict__ bsum,
                                   int* __restrict__ offsets, int N, int E) {
    __shared__ int s[256];
    int t = threadIdx.x;
    int i = blockIdx.x * 256 + t;
    int mine = (i < N) ? counts[i] : 0;
    s[t] = mine;
    __syncthreads();
    for (int off = 1; off < 256; off <<= 1) {
        int v = (t >= off) ? s[t - off] : 0;
        __syncthreads();
        s[t] += v;
        __syncthreads();
    }
    if (i < N) offsets[i] = bsum[blockIdx.x] + s[t] - mine;
    if (i == 0 && blockIdx.x == 0) offsets[N] = E;
}

// Bucket edges by dst: src_sorted[offsets[d] + slot] = src[e]
__global__ void bucket_kernel(const int* __restrict__ src, const int* __restrict__ dst,
                              const int* __restrict__ offsets, int* __restrict__ cursor,
                              int* __restrict__ src_sorted, int E) {
    int i = blockIdx.x * blockDim.x + threadIdx.x;
    if (i < E) {
        int d = dst[i];
        int pos = atomicAdd(&cursor[d], 1);
        src_sorted[offsets[d] + pos] = src[i];
    }
}

// One 64-lane wave per node. Lanes split into 2 halves of 32; each half
// handles alternate incoming edges; lane covers one float4 of the row.
__global__ void gather_kernel(const float* __restrict__ weight,
                              const float* __restrict__ cj,
                              const float* __restrict__ ci,
                              const int* __restrict__ offsets,
                              const int* __restrict__ src_sorted,
                              float* __restrict__ out, int N) {
    int gt = blockIdx.x * blockDim.x + threadIdx.x;
    int node = gt >> 6;
    if (node >= N) return;                 // node uniform per wave -> no divergence
    int lane = gt & 63;
    int fi   = (lane & 31) << 2;           // float offset within row
    int half = lane >> 5;
    int start = offsets[node];
    int end   = offsets[node + 1];
    float4 acc = make_float4(0.f, 0.f, 0.f, 0.f);
    for (int k = start + half; k < end; k += 2) {
        int s = src_sorted[k];
        float c = cj[s];
        const float4 w = *reinterpret_cast<const float4*>(weight + (size_t)s * FEAT + fi);
        acc.x += w.x * c; acc.y += w.y * c; acc.z += w.z * c; acc.w += w.w * c;
    }
    // combine the two halves (lane <-> lane^32)
    acc.x += __shfl_xor(acc.x, 32);
    acc.y += __shfl_xor(acc.y, 32);
    acc.z += __shfl_xor(acc.z, 32);
    acc.w += __shfl_xor(acc.w, 32);
    if (half == 0) {
        float c = ci[node];
        float4 r = make_float4(acc.x * c, acc.y * c, acc.z * c, acc.w * c);
        *reinterpret_cast<float4*>(out + (size_t)node * FEAT + fi) = r;
    }
}

// ---------------------------------------------------------------------------
// Fallback path (round-1 verified): float atomics
// ---------------------------------------------------------------------------

__global__ void gcmc_zero_kernel(float4* __restrict__ out, int n4) {
    int i = blockIdx.x * blockDim.x + threadIdx.x;
    if (i < n4) out[i] = make_float4(0.f, 0.f, 0.f, 0.f);
}

__global__ void gcmc_scatter_kernel(const float* __restrict__ weight,
                                    const float* __restrict__ cj,
                                    const int* __restrict__ src,
                                    const int* __restrict__ dst,
                                    float* __restrict__ out,
                                    int n_edges) {
    int t = blockIdx.x * blockDim.x + threadIdx.x;
    int e = t >> 5;
    int f = (t & 31) << 2;
    if (e >= n_edges) return;
    int s = src[e];
    int d = dst[e];
    float c = cj[s];
    const float4 w = *reinterpret_cast<const float4*>(weight + (size_t)s * FEAT + f);
    float* o = out + (size_t)d * FEAT + f;
    unsafeAtomicAdd(o + 0, w.x * c);
    unsafeAtomicAdd(o + 1, w.y * c);
    unsafeAtomicAdd(o + 2, w.z * c);
    unsafeAtomicAdd(o + 3, w.w * c);
}

__global__ void gcmc_scale_kernel(float4* __restrict__ out,
                                  const float* __restrict__ ci, int n4) {
    int i = blockIdx.x * blockDim.x + threadIdx.x;
    if (i < n4) {
        float c = ci[i >> 5];
        float4 v = out[i];
        v.x *= c; v.y *= c; v.z *= c; v.w *= c;
        out[i] = v;
    }
}

// ---------------------------------------------------------------------------

extern "C" void kernel_launch(void* const* d_in, const int* in_sizes, int n_in,
                              void* d_out, int out_size, void* d_ws, size_t ws_size,
                              hipStream_t stream) {
    const float* weight = (const float*)d_in[0];
    const float* cj     = (const float*)d_in[1];
    const float* ci     = (const float*)d_in[2];
    const int*   src    = (const int*)d_in[3];
    const int*   dst    = (const int*)d_in[4];
    float* out = (float*)d_out;

    const int N = in_sizes[1];             // cj is [N,1]
    const int E = in_sizes[3];

    const int NB = (N + 255) / 256;        // blocks for per-node arrays

    // workspace layout (ints), 256B-aligned sections
    size_t off_offsets = 0;                                   // (N+1) ints
    size_t off_cursor  = ((off_offsets + (size_t)(N + 1) * 4 + 255) / 256) * 256; // N ints
    size_t off_bsum    = ((off_cursor + (size_t)N * 4 + 255) / 256) * 256;        // 512 ints
    size_t off_srcs    = ((off_bsum + 512 * 4 + 255) / 256) * 256;                // E ints
    size_t need        = off_srcs + (size_t)E * 4;

    if (ws_size >= need && NB <= 512) {
        char* ws = (char*)d_ws;
        int* offsets    = (int*)(ws + off_offsets);
        int* cursor     = (int*)(ws + off_cursor);
        int* bsum       = (int*)(ws + off_bsum);
        int* src_sorted = (int*)(ws + off_srcs);

        // counts live in `cursor` first (zero -> histogram), then are consumed
        // by the scan into `offsets`; cursor is re-zeroed for bucket slots.
        zero_ints_kernel<<<NB, 256, 0, stream>>>(cursor, N);
        hist_kernel<<<(E + 255) / 256, 256, 0, stream>>>(dst, cursor, E);
        block_sum_kernel<<<NB, 256, 0, stream>>>(cursor, bsum, N);
        scan_bsum_kernel<<<1, 512, 0, stream>>>(bsum, NB);
        scan_counts_kernel<<<NB, 256, 0, stream>>>(cursor, bsum, offsets, N, E);
        zero_ints_kernel<<<NB, 256, 0, stream>>>(cursor, N);
        bucket_kernel<<<(E + 255) / 256, 256, 0, stream>>>(src, dst, offsets, cursor,
                                                           src_sorted, E);
        // one wave (64 threads) per node
        long threads = (long)N * 64;
        gather_kernel<<<(int)((threads + 255) / 256), 256, 0, stream>>>(
            weight, cj, ci, offsets, src_sorted, out, N);
    } else {
        // fallback: verified atomic path
        const int total = N * FEAT;
        const int n4 = total >> 2;
        gcmc_zero_kernel<<<(n4 + 255) / 256, 256, 0, stream>>>((float4*)out, n4);
        const long threads = (long)E * 32;
        gcmc_scatter_kernel<<<(int)((threads + 255) / 256), 256, 0, stream>>>(
            weight, cj, src, dst, out, E);
        gcmc_scale_kernel<<<(n4 + 255) / 256, 256, 0, stream>>>((float4*)out, ci, n4);
    }
}

// Round 3
// 276.010 us; speedup vs baseline: 9.7492x; 1.0251x over previous
//
#include <hip/hip_runtime.h>
#include <hip/hip_bf16.h>

#define FEAT 128

__device__ __forceinline__ unsigned short f2b(float f) {
    __hip_bfloat16 h = __float2bfloat16(f);   // RNE
    return *reinterpret_cast<unsigned short*>(&h);
}
__device__ __forceinline__ float b2f(unsigned short u) {
    unsigned int x = ((unsigned int)u) << 16;
    float f;
    __builtin_memcpy(&f, &x, 4);
    return f;
}
__device__ __forceinline__ unsigned int pack2(float lo, float hi) {
    return (unsigned int)f2b(lo) | ((unsigned int)f2b(hi) << 16);
}

// ---------------------------------------------------------------------------
// CSR-build + bf16-feature gather path (no float atomics)
// ---------------------------------------------------------------------------

__global__ void zero_ints_kernel(int* __restrict__ p, int n) {
    int i = blockIdx.x * blockDim.x + threadIdx.x;
    if (i < n) p[i] = 0;
}

// Fused: (a) feat16[row] = bf16(weight[row] * cj[row]), 8 feats/thread
//        (b) histogram of dst into counts
__global__ void convert_hist_kernel(const float* __restrict__ weight,
                                    const float* __restrict__ cj,
                                    const int* __restrict__ dst,
                                    int* __restrict__ counts,
                                    unsigned short* __restrict__ feat16,
                                    int N, int E) {
    int i = blockIdx.x * blockDim.x + threadIdx.x;
    int NC = N * (FEAT / 8);
    if (i < NC) {
        int row = i >> 4;            // FEAT/8 = 16 threads per row
        int seg = i & 15;
        float c = cj[row];
        const float4* p = reinterpret_cast<const float4*>(
            weight + (size_t)row * FEAT + seg * 8);
        float4 a = p[0], b = p[1];
        uint4 o;
        o.x = pack2(a.x * c, a.y * c);
        o.y = pack2(a.z * c, a.w * c);
        o.z = pack2(b.x * c, b.y * c);
        o.w = pack2(b.z * c, b.w * c);
        *reinterpret_cast<uint4*>(feat16 + (size_t)i * 8) = o;
    }
    if (i < E) atomicAdd(&counts[dst[i]], 1);
}

// Per-block sum of 256 counts -> bsum[block]
__global__ void block_sum_kernel(const int* __restrict__ counts, int* __restrict__ bsum, int N) {
    __shared__ int s[256];
    int i = blockIdx.x * 256 + threadIdx.x;
    s[threadIdx.x] = (i < N) ? counts[i] : 0;
    __syncthreads();
    for (int off = 128; off > 0; off >>= 1) {
        if (threadIdx.x < off) s[threadIdx.x] += s[threadIdx.x + off];
        __syncthreads();
    }
    if (threadIdx.x == 0) bsum[blockIdx.x] = s[0];
}

// Single-block exclusive scan of bsum[0..nb), nb <= 512
__global__ void scan_bsum_kernel(int* __restrict__ bsum, int nb) {
    __shared__ int s[512];
    int t = threadIdx.x;
    int mine = (t < nb) ? bsum[t] : 0;
    s[t] = mine;
    __syncthreads();
    for (int off = 1; off < 512; off <<= 1) {
        int v = (t >= off) ? s[t - off] : 0;
        __syncthreads();
        s[t] += v;
        __syncthreads();
    }
    if (t < nb) bsum[t] = s[t] - mine;   // exclusive
}

// Per-block exclusive scan of counts + block offset -> offsets; offsets[N]=E
// Also seeds cursor[i] = offsets[i] (bucket uses it as its write cursor).
__global__ void scan_counts_kernel(const int* __restrict__ counts, const int* __restrict__ bsum,
                                   int* __restrict__ offsets, int* __restrict__ cursor,
                                   int N, int E) {
    __shared__ int s[256];
    int t = threadIdx.x;
    int i = blockIdx.x * 256 + t;
    int mine = (i < N) ? counts[i] : 0;
    s[t] = mine;
    __syncthreads();
    for (int off = 1; off < 256; off <<= 1) {
        int v = (t >= off) ? s[t - off] : 0;
        __syncthreads();
        s[t] += v;
        __syncthreads();
    }
    if (i < N) {
        int o = bsum[blockIdx.x] + s[t] - mine;
        offsets[i] = o;
        cursor[i] = o;
    }
    if (i == 0 && blockIdx.x == 0) offsets[N] = E;
}

// Bucket edges by dst: src_sorted[atomicAdd(cursor[d],1)] = src[e]
__global__ void bucket_kernel(const int* __restrict__ src, const int* __restrict__ dst,
                              int* __restrict__ cursor,
                              int* __restrict__ src_sorted, int E) {
    int i = blockIdx.x * blockDim.x + threadIdx.x;
    if (i < E) {
        int pos = atomicAdd(&cursor[dst[i]], 1);
        src_sorted[pos] = src[i];
    }
}

// One 64-lane wave per node; two 32-lane halves alternate edges; each lane
// covers 4 features (8 B bf16 load per edge).
__global__ void gather_kernel(const unsigned short* __restrict__ feat16,
                              const float* __restrict__ ci,
                              const int* __restrict__ offsets,
                              const int* __restrict__ src_sorted,
                              float* __restrict__ out, int N) {
    int gt = blockIdx.x * blockDim.x + threadIdx.x;
    int node = gt >> 6;
    if (node >= N) return;                 // node uniform per wave
    int lane = gt & 63;
    int fi   = (lane & 31) << 2;           // feature offset (0..124)
    int half = lane >> 5;
    int start = offsets[node];
    int end   = offsets[node + 1];
    float4 acc = make_float4(0.f, 0.f, 0.f, 0.f);
    #pragma unroll 2
    for (int k = start + half; k < end; k += 2) {
        int s = src_sorted[k];
        ushort4 w = *reinterpret_cast<const ushort4*>(feat16 + (size_t)s * FEAT + fi);
        acc.x += b2f(w.x);
        acc.y += b2f(w.y);
        acc.z += b2f(w.z);
        acc.w += b2f(w.w);
    }
    acc.x += __shfl_xor(acc.x, 32);
    acc.y += __shfl_xor(acc.y, 32);
    acc.z += __shfl_xor(acc.z, 32);
    acc.w += __shfl_xor(acc.w, 32);
    if (half == 0) {
        float c = ci[node];
        float4 r = make_float4(acc.x * c, acc.y * c, acc.z * c, acc.w * c);
        *reinterpret_cast<float4*>(out + (size_t)node * FEAT + fi) = r;
    }
}

// ---------------------------------------------------------------------------
// Fallback path (round-1 verified): float atomics
// ---------------------------------------------------------------------------

__global__ void gcmc_zero_kernel(float4* __restrict__ out, int n4) {
    int i = blockIdx.x * blockDim.x + threadIdx.x;
    if (i < n4) out[i] = make_float4(0.f, 0.f, 0.f, 0.f);
}

__global__ void gcmc_scatter_kernel(const float* __restrict__ weight,
                                    const float* __restrict__ cj,
                                    const int* __restrict__ src,
                                    const int* __restrict__ dst,
                                    float* __restrict__ out,
                                    int n_edges) {
    int t = blockIdx.x * blockDim.x + threadIdx.x;
    int e = t >> 5;
    int f = (t & 31) << 2;
    if (e >= n_edges) return;
    int s = src[e];
    int d = dst[e];
    float c = cj[s];
    const float4 w = *reinterpret_cast<const float4*>(weight + (size_t)s * FEAT + f);
    float* o = out + (size_t)d * FEAT + f;
    unsafeAtomicAdd(o + 0, w.x * c);
    unsafeAtomicAdd(o + 1, w.y * c);
    unsafeAtomicAdd(o + 2, w.z * c);
    unsafeAtomicAdd(o + 3, w.w * c);
}

__global__ void gcmc_scale_kernel(float4* __restrict__ out,
                                  const float* __restrict__ ci, int n4) {
    int i = blockIdx.x * blockDim.x + threadIdx.x;
    if (i < n4) {
        float c = ci[i >> 5];
        float4 v = out[i];
        v.x *= c; v.y *= c; v.z *= c; v.w *= c;
        out[i] = v;
    }
}

// ---------------------------------------------------------------------------

extern "C" void kernel_launch(void* const* d_in, const int* in_sizes, int n_in,
                              void* d_out, int out_size, void* d_ws, size_t ws_size,
                              hipStream_t stream) {
    const float* weight = (const float*)d_in[0];
    const float* cj     = (const float*)d_in[1];
    const float* ci     = (const float*)d_in[2];
    const int*   src    = (const int*)d_in[3];
    const int*   dst    = (const int*)d_in[4];
    float* out = (float*)d_out;

    const int N = in_sizes[1];             // cj is [N,1]
    const int E = in_sizes[3];

    const int NB = (N + 255) / 256;        // blocks for per-node arrays

    // workspace layout, 256B-aligned sections
    size_t off_offsets = 0;                                                        // (N+1) ints
    size_t off_cursor  = ((off_offsets + (size_t)(N + 1) * 4 + 255) / 256) * 256;  // N ints
    size_t off_bsum    = ((off_cursor + (size_t)N * 4 + 255) / 256) * 256;         // 512 ints
    size_t off_srcs    = ((off_bsum + 512 * 4 + 255) / 256) * 256;                 // E ints
    size_t off_feat    = ((off_srcs + (size_t)E * 4 + 255) / 256) * 256;           // N*FEAT ushorts
    size_t need        = off_feat + (size_t)N * FEAT * 2;

    if (ws_size >= need && NB <= 512) {
        char* ws = (char*)d_ws;
        int* offsets    = (int*)(ws + off_offsets);
        int* cursor     = (int*)(ws + off_cursor);   // counts, then write cursor
        int* bsum       = (int*)(ws + off_bsum);
        int* src_sorted = (int*)(ws + off_srcs);
        unsigned short* feat16 = (unsigned short*)(ws + off_feat);

        zero_ints_kernel<<<NB, 256, 0, stream>>>(cursor, N);
        {
            long T = (long)N * (FEAT / 8);
            if ((long)E > T) T = E;
            convert_hist_kernel<<<(int)((T + 255) / 256), 256, 0, stream>>>(
                weight, cj, dst, cursor, feat16, N, E);
        }
        block_sum_kernel<<<NB, 256, 0, stream>>>(cursor, bsum, N);
        scan_bsum_kernel<<<1, 512, 0, stream>>>(bsum, NB);
        scan_counts_kernel<<<NB, 256, 0, stream>>>(cursor, bsum, offsets, cursor, N, E);
        bucket_kernel<<<(E + 255) / 256, 256, 0, stream>>>(src, dst, cursor, src_sorted, E);
        long threads = (long)N * 64;
        gather_kernel<<<(int)((threads + 255) / 256), 256, 0, stream>>>(
            feat16, ci, offsets, src_sorted, out, N);
    } else {
        // fallback: verified atomic path (exact f32)
        const int total = N * FEAT;
        const int n4 = total >> 2;
        gcmc_zero_kernel<<<(n4 + 255) / 256, 256, 0, stream>>>((float4*)out, n4);
        const long threads = (long)E * 32;
        gcmc_scatter_kernel<<<(int)((threads + 255) / 256), 256, 0, stream>>>(
            weight, cj, src, dst, out, E);
        gcmc_scale_kernel<<<(n4 + 255) / 256, 256, 0, stream>>>((float4*)out, ci, n4);
    }
}